// Round 4
// baseline (329.255 us; speedup 1.0000x reference)
//
#include <hip/hip_runtime.h>
#include <hip/hip_cooperative_groups.h>

namespace cg = cooperative_groups;

#define K_ELL 32   // ELL width for b-side adjacency (max b-degree in MC-tet meshes ~<=14)
#define NBLK  768  // 3 blocks/CU on 256 CUs -- co-resident with <=128 VGPRs
#define BS    256

__device__ __forceinline__ void gather_one(int u, const float* __restrict__ x,
                                           const int2* __restrict__ edges,
                                           const int* __restrict__ offs_a,
                                           const int* __restrict__ deg_b,
                                           const int* __restrict__ adj_b,
                                           float* __restrict__ y) {
    int aBeg = offs_a[u], aEnd = offs_a[u + 1];
    int dbFull = deg_b[u];
    int db = dbFull > K_ELL ? K_ELL : dbFull;
    const int* __restrict__ row = adj_b + (size_t)u * K_ELL;
    float s0 = 0.f, s1 = 0.f, s2 = 0.f;
    for (int i = aBeg; i < aEnd; i++) {
        int n = edges[i].y;
        s0 += x[3 * n + 0]; s1 += x[3 * n + 1]; s2 += x[3 * n + 2];
    }
    for (int k = 0; k < db; k++) {
        int n = row[k];
        s0 += x[3 * n + 0]; s1 += x[3 * n + 1]; s2 += x[3 * n + 2];
    }
    int d = (aEnd - aBeg) + dbFull;
    float inv = 1.0f / fmaxf((float)d, 1.0f);
    // lambd == 1.0: x + (s*inv - x) == s*inv (deg==0 -> s=0, inv=1 -> 0, matches ref)
    y[3 * u + 0] = s0 * inv;
    y[3 * u + 1] = s1 * inv;
    y[3 * u + 2] = s2 * inv;
}

__global__ __launch_bounds__(BS, 4) void fused_kernel(
        const int2* __restrict__ edges, const int* __restrict__ faces,
        const float* __restrict__ v, float* __restrict__ out_v, float* __restrict__ out_f,
        int* __restrict__ deg_b, int* __restrict__ offs_a, int* __restrict__ adj_b,
        float* __restrict__ x1, int E, int V, int F3) {
    cg::grid_group grid = cg::this_grid();
    const int tid = blockIdx.x * blockDim.x + threadIdx.x;
    const int T = gridDim.x * blockDim.x;

    // phase 0: zero b-side degree counters (ws is poisoned 0xAA each call)
    for (int i = tid; i < V; i += T) deg_b[i] = 0;
    grid.sync();

    // phase 1: build a-side segment boundaries (edges[:,0] sorted ascending, a<b
    // guaranteed by np.unique(np.sort(e,1),axis=0)), b-side ELL via rank-capturing
    // atomics, and the faces->float copy.
    for (int i = tid; i <= E; i += T) {
        if (i < E) {
            int2 e = edges[i];
            int r = atomicAdd(&deg_b[e.y], 1);
            if (r < K_ELL) adj_b[(size_t)e.y * K_ELL + r] = e.x;
            int lo = (i == 0) ? 0 : edges[i - 1].x + 1;
            for (int a = lo; a <= e.x; a++) offs_a[a] = i;   // offs_a[v]=first edge with a>=v
        } else {
            for (int a = edges[E - 1].x + 1; a <= V; a++) offs_a[a] = E;  // tail incl offs_a[V]
        }
    }
    for (int j = tid; j < F3; j += T) out_f[j] = (float)faces[j];
    grid.sync();

    // phase 2: smoothing iteration 1: v -> x1
    for (int u = tid; u < V; u += T)
        gather_one(u, v, edges, offs_a, deg_b, adj_b, x1);
    grid.sync();

    // phase 3: smoothing iteration 2: x1 -> out_v
    for (int u = tid; u < V; u += T)
        gather_one(u, x1, edges, offs_a, deg_b, adj_b, out_v);
}

extern "C" void kernel_launch(void* const* d_in, const int* in_sizes, int n_in,
                              void* d_out, int out_size, void* d_ws, size_t ws_size,
                              hipStream_t stream) {
    const int2* edges = (const int2*)d_in[1];   // [E,2], rows lex-sorted, a<b
    const int*  faces = (const int*)d_in[2];    // [F,3]
    const float* v    = (const float*)d_in[0];  // [V,3]

    int V3 = in_sizes[0];
    int V  = V3 / 3;
    int E  = in_sizes[1] / 2;
    int F3 = in_sizes[2];

    float* out_v = (float*)d_out;
    float* out_f = (float*)d_out + V3;

    // ws layout (4B words): deg_b[V] | offs_a[V+1] | adj_b[V*K_ELL] | x1[3V]
    int*   deg_b  = (int*)d_ws;
    int*   offs_a = deg_b + V;
    int*   adj_b  = offs_a + (V + 1);
    float* x1     = (float*)(adj_b + (size_t)V * K_ELL);

    void* args[] = {(void*)&edges, (void*)&faces, (void*)&v, (void*)&out_v, (void*)&out_f,
                    (void*)&deg_b, (void*)&offs_a, (void*)&adj_b, (void*)&x1,
                    (void*)&E, (void*)&V, (void*)&F3};
    hipLaunchCooperativeKernel((const void*)fused_kernel, dim3(NBLK), dim3(BS),
                               args, 0, stream);
}

// Round 5
// 102.783 us; speedup vs baseline: 3.2034x; 3.2034x over previous
//
#include <hip/hip_runtime.h>

#define K_ELL 32   // ELL width for b-side adjacency (max b-degree in MC-tet meshes << 32)
#define BS    256

// build: a-side segment boundaries (edges[:,0] sorted ascending, a<b guaranteed by
// np.unique(np.sort(e,1),axis=0)), b-side ELL via rank-capturing atomics,
// faces->float copy, and v -> padded float4 repack.
__global__ void build_kernel(const int2* __restrict__ edges, const int* __restrict__ faces,
                             const float* __restrict__ v, float4* __restrict__ v4,
                             int* __restrict__ deg_b, int* __restrict__ offs_a,
                             int* __restrict__ adj_b, float* __restrict__ out_f,
                             int E, int V, int F3) {
    const int tid = blockIdx.x * blockDim.x + threadIdx.x;
    const int T = gridDim.x * blockDim.x;

    for (int i = tid; i <= E; i += T) {
        if (i < E) {
            int2 e = edges[i];
            int r = atomicAdd(&deg_b[e.y], 1);           // only atomics in the pipeline
            if (r < K_ELL) adj_b[(size_t)e.y * K_ELL + r] = e.x;
            int lo = (i == 0) ? 0 : edges[i - 1].x + 1;  // offs_a[u] = first edge with a >= u
            for (int a = lo; a <= e.x; a++) offs_a[a] = i;
        } else {
            for (int a = edges[E - 1].x + 1; a <= V; a++) offs_a[a] = E;  // tail incl offs_a[V]
        }
    }
    for (int j = tid; j < F3; j += T) out_f[j] = (float)faces[j];
    for (int u = tid; u < V; u += T)
        v4[u] = make_float4(v[3 * u], v[3 * u + 1], v[3 * u + 2], 0.f);
}

// One smoothing iteration (lambd==1 -> y = nbr_sum/deg; deg==0 -> 0, matches ref).
// PAD: write padded float4 (intermediate) vs tight [V,3] floats (final output).
template <bool PAD>
__global__ void gather_kernel(const float4* __restrict__ x4, const int2* __restrict__ edges,
                              const int* __restrict__ offs_a, const int* __restrict__ deg_b,
                              const int* __restrict__ adj_b, float* __restrict__ y, int V) {
    int u = blockIdx.x * blockDim.x + threadIdx.x;
    if (u >= V) return;
    int aBeg = offs_a[u], aEnd = offs_a[u + 1];
    int dbFull = deg_b[u];
    int db = dbFull > K_ELL ? K_ELL : dbFull;
    const int* __restrict__ row = adj_b + (size_t)u * K_ELL;
    float s0 = 0.f, s1 = 0.f, s2 = 0.f;
    for (int i = aBeg; i < aEnd; i++) {
        float4 p = x4[edges[i].y];                       // one dwordx4 per neighbor
        s0 += p.x; s1 += p.y; s2 += p.z;
    }
    for (int k = 0; k < db; k++) {
        float4 p = x4[row[k]];
        s0 += p.x; s1 += p.y; s2 += p.z;
    }
    int d = (aEnd - aBeg) + dbFull;
    float inv = 1.0f / fmaxf((float)d, 1.0f);
    if (PAD) {
        ((float4*)y)[u] = make_float4(s0 * inv, s1 * inv, s2 * inv, 0.f);
    } else {
        y[3 * u + 0] = s0 * inv;
        y[3 * u + 1] = s1 * inv;
        y[3 * u + 2] = s2 * inv;
    }
}

extern "C" void kernel_launch(void* const* d_in, const int* in_sizes, int n_in,
                              void* d_out, int out_size, void* d_ws, size_t ws_size,
                              hipStream_t stream) {
    const float* v     = (const float*)d_in[0];  // [V,3]
    const int2*  edges = (const int2*)d_in[1];   // [E,2], rows lex-sorted, a<b
    const int*   faces = (const int*)d_in[2];    // [F,3]

    const int V3 = in_sizes[0];
    const int V  = V3 / 3;
    const int E  = in_sizes[1] / 2;
    const int F3 = in_sizes[2];

    float* out_v = (float*)d_out;
    float* out_f = (float*)d_out + V3;

    // ws layout (16B-aligned first): v4[V] | x1[V] (both float4) | adj_b[V*K_ELL] |
    //                                deg_b[V] | offs_a[V+1]
    float4* v4     = (float4*)d_ws;
    float4* x1     = v4 + V;
    int*    adj_b  = (int*)(x1 + V);
    int*    deg_b  = adj_b + (size_t)V * K_ELL;
    int*    offs_a = deg_b + V;

    const int gB = ((F3 > E + 1 ? F3 : E + 1) + BS - 1) / BS;
    const int gV = (V + BS - 1) / BS;

    hipMemsetAsync(deg_b, 0, (size_t)V * sizeof(int), stream);

    build_kernel<<<gB, BS, 0, stream>>>(edges, faces, v, v4, deg_b, offs_a, adj_b,
                                        out_f, E, V, F3);

    gather_kernel<true ><<<gV, BS, 0, stream>>>(v4, edges, offs_a, deg_b, adj_b,
                                                (float*)x1, V);
    gather_kernel<false><<<gV, BS, 0, stream>>>(x1, edges, offs_a, deg_b, adj_b,
                                                out_v, V);
}

// Round 6
// 99.007 us; speedup vs baseline: 3.3256x; 1.0381x over previous
//
#include <hip/hip_runtime.h>

#define K_ELL 32   // ELL width (column-major: unused planes cost 0 traffic, only ws bytes)
#define BS    256

// build: a-side segment boundaries (edges[:,0] sorted ascending, a<b guaranteed by
// np.unique(np.sort(e,1),axis=0)), b-side column-major ELL via rank-capturing atomics,
// faces->float copy, and v -> padded float4 repack.
__global__ void build_kernel(const int2* __restrict__ edges, const int* __restrict__ faces,
                             const float* __restrict__ v, float4* __restrict__ v4,
                             int* __restrict__ deg_b, int* __restrict__ offs_a,
                             int* __restrict__ adj_b, float* __restrict__ out_f,
                             int E, int V, int F3) {
    const int tid = blockIdx.x * blockDim.x + threadIdx.x;
    const int T = gridDim.x * blockDim.x;

    for (int i = tid; i <= E; i += T) {
        if (i < E) {
            int2 e = edges[i];
            int r = atomicAdd(&deg_b[e.y], 1);            // only atomics in the pipeline
            if (r < K_ELL) adj_b[(size_t)r * V + e.y] = e.x;   // column-major plane write
            int lo = (i == 0) ? 0 : edges[i - 1].x + 1;   // offs_a[u] = first edge with a >= u
            for (int a = lo; a <= e.x; a++) offs_a[a] = i;
        } else {
            for (int a = edges[E - 1].x + 1; a <= V; a++) offs_a[a] = E;  // tail incl offs_a[V]
        }
    }
    for (int j = tid; j < F3; j += T) out_f[j] = (float)faces[j];
    for (int u = tid; u < V; u += T)
        v4[u] = make_float4(v[3 * u], v[3 * u + 1], v[3 * u + 2], 0.f);
}

// One smoothing iteration (lambd==1 -> y = nbr_sum/deg; deg==0 -> 0, matches ref).
// PAD: write padded float4 (intermediate) vs tight [V,3] floats (final output).
template <bool PAD>
__global__ void gather_kernel(const float4* __restrict__ x4, const int2* __restrict__ edges,
                              const int* __restrict__ offs_a, const int* __restrict__ deg_b,
                              const int* __restrict__ adj_b, float* __restrict__ y, int V) {
    int u = blockIdx.x * blockDim.x + threadIdx.x;
    if (u >= V) return;
    int aBeg = offs_a[u], aEnd = offs_a[u + 1];
    int dbFull = deg_b[u];
    int db = dbFull > K_ELL ? K_ELL : dbFull;
    float s0 = 0.f, s1 = 0.f, s2 = 0.f;
    for (int i = aBeg; i < aEnd; i++) {
        float4 p = x4[edges[i].y];                        // one dwordx4 per neighbor
        s0 += p.x; s1 += p.y; s2 += p.z;
    }
    for (int k = 0; k < db; k++) {
        int n = adj_b[(size_t)k * V + u];                 // coalesced across u
        float4 p = x4[n];
        s0 += p.x; s1 += p.y; s2 += p.z;
    }
    int d = (aEnd - aBeg) + dbFull;
    float inv = 1.0f / fmaxf((float)d, 1.0f);
    if (PAD) {
        ((float4*)y)[u] = make_float4(s0 * inv, s1 * inv, s2 * inv, 0.f);
    } else {
        y[3 * u + 0] = s0 * inv;
        y[3 * u + 1] = s1 * inv;
        y[3 * u + 2] = s2 * inv;
    }
}

extern "C" void kernel_launch(void* const* d_in, const int* in_sizes, int n_in,
                              void* d_out, int out_size, void* d_ws, size_t ws_size,
                              hipStream_t stream) {
    const float* v     = (const float*)d_in[0];  // [V,3]
    const int2*  edges = (const int2*)d_in[1];   // [E,2], rows lex-sorted, a<b
    const int*   faces = (const int*)d_in[2];    // [F,3]

    const int V3 = in_sizes[0];
    const int V  = V3 / 3;
    const int E  = in_sizes[1] / 2;
    const int F3 = in_sizes[2];

    float* out_v = (float*)d_out;
    float* out_f = (float*)d_out + V3;

    // ws layout (16B-aligned first): v4[V] | x1[V] (float4) | adj_b[K_ELL*V] |
    //                                deg_b[V] | offs_a[V+1]
    float4* v4     = (float4*)d_ws;
    float4* x1     = v4 + V;
    int*    adj_b  = (int*)(x1 + V);
    int*    deg_b  = adj_b + (size_t)K_ELL * V;
    int*    offs_a = deg_b + V;

    const int gB = ((F3 > E + 1 ? F3 : E + 1) + BS - 1) / BS;
    const int gV = (V + BS - 1) / BS;

    hipMemsetAsync(deg_b, 0, (size_t)V * sizeof(int), stream);

    build_kernel<<<gB, BS, 0, stream>>>(edges, faces, v, v4, deg_b, offs_a, adj_b,
                                        out_f, E, V, F3);

    gather_kernel<true ><<<gV, BS, 0, stream>>>(v4, edges, offs_a, deg_b, adj_b,
                                                (float*)x1, V);
    gather_kernel<false><<<gV, BS, 0, stream>>>(x1, edges, offs_a, deg_b, adj_b,
                                                out_v, V);
}